// Round 17
// baseline (248.234 us; speedup 1.0000x reference)
//
#include <hip/hip_runtime.h>
#include <cmath>

#define NB 8
#define NN 4096
#define DF 128
#define NH 4
#define NJ 32
#define NK 128
#define NTOT (NB*NN)          // 32768
#define ETOT 524288           // 8 * 4096 * 16
#define BPB (NH*NB*NJ)        // 1024
#define DHID 256
#define NCLS 16
#define CAP_PB 96             // per (part, blk) LDS bucket capacity (avg ~8)
#define CAP_BP 512            // per-bpid elist segment capacity (avg ~64)

#define FP_SCALE 4194304.0    // 2^22 fixed-point for deterministic score accumulation
#define FP_INV   (1.0/4194304.0)

typedef short bf16x8 __attribute__((ext_vector_type(8)));
typedef float f32x4  __attribute__((ext_vector_type(4)));

__device__ __forceinline__ unsigned short f2bf(float f) {
    unsigned u = __float_as_uint(f);
    unsigned r = (u + 0x7FFFu + ((u >> 16) & 1u)) >> 16;   // RNE
    return (unsigned short)r;
}
__device__ __forceinline__ float bf2f(unsigned short b) {
    unsigned u = ((unsigned)b) << 16;
    return __uint_as_float(u);
}

// sortable u64 key: ascending k64 == (descending score, ascending idx) — matches argsort(-s) stable
__device__ __forceinline__ unsigned long long make_key(float sc, int p) {
    unsigned u = __float_as_uint(sc);
    unsigned s = u ^ ((unsigned)((int)u >> 31) | 0x80000000u);   // ascending-float map
    return ((unsigned long long)(s ^ 0xFFFFFFFFu) << 12) | (unsigned)p;
}

// ---------------- init ----------------
__global__ void k0_init(int* deg_i, int* fill, int* fill2, int* done) {
    int t = blockIdx.x * blockDim.x + threadIdx.x;
    if (t < NTOT) { deg_i[t] = 0; fill2[t] = 0; }
    if (t < BPB) fill[t] = 0;
    if (t == 0) *done = 0;
}

// fused: [0,2048) deg atomics (XCD-swizzled) | [2048,4096) x->bf16
//        [4096,4352) W1T | [4352,4480) scores (1 thread = 1 node x 4 heads)
__global__ __launch_bounds__(256) void k1_deg_prep(const int* __restrict__ ei,
                                                   const float* __restrict__ x,
                                                   const float* __restrict__ W1,
                                                   const float* __restrict__ wr,
                                                   int* deg_i,
                                                   unsigned short* __restrict__ xbf,
                                                   unsigned short* __restrict__ w1t,
                                                   float* __restrict__ scores_pre) {
    int bid = blockIdx.x, tid = threadIdx.x;
    if (bid < 2048) {                       // in-degree; batch = bid&7 -> same XCD L2
        int e = (bid & 7) * 65536 + (bid >> 3) * 256 + tid;
        atomicAdd(&deg_i[ei[ETOT + e]], 1);
    } else if (bid < 4096) {                // x -> bf16, 8 elems/thread
        int idx = (bid - 2048) * 256 + tid;
        const float* sp = x + (size_t)idx * 8;
        float4 lo = *(const float4*)sp;
        float4 hi = *(const float4*)(sp + 4);
        unsigned short u[8] = {f2bf(lo.x), f2bf(lo.y), f2bf(lo.z), f2bf(lo.w),
                               f2bf(hi.x), f2bf(hi.y), f2bf(hi.z), f2bf(hi.w)};
        *(bf16x8*)(xbf + (size_t)idx * 8) = *(bf16x8*)u;
    } else if (bid < 4352) {                // W1T bf16
        int t = (bid - 4096) * 256 + tid;
        int k = t >> 8, n = t & 255;
        w1t[n * 256 + k] = f2bf(W1[k * DHID + n]);
    } else {                                // scores: 1 node, 4 heads; d0-order kept per head
        int g = (bid - 4352) * 256 + tid;   // node id, 32768
        const float* xr = x + (size_t)g * DF;
        const float4* wr4 = (const float4*)wr;
        double a0 = 0.0, a1 = 0.0, a2 = 0.0, a3 = 0.0;
        for (int d0 = 0; d0 < DF; ++d0) {
            double xv = (double)xr[d0];
            float4 w = wr4[d0];
            a0 += xv * (double)w.x;
            a1 += xv * (double)w.y;
            a2 += xv * (double)w.z;
            a3 += xv * (double)w.w;
        }
        float4 o = {(float)a0, (float)a1, (float)a2, (float)a3};
        ((float4*)scores_pre)[g] = o;
    }
}

// fused: [0,128) rdeg | bid==128: exclusive deg scan (two-pass, 256 thr x 128 elems)
__global__ __launch_bounds__(256) void k_prep2(const int* __restrict__ deg_i,
                                               float* __restrict__ rdeg,
                                               int* __restrict__ nbase) {
    int bid = blockIdx.x, tid = threadIdx.x;
    if (bid < 128) {
        int t = bid * 256 + tid;
        rdeg[t] = 1.0f / sqrtf((float)(1 + deg_i[t]));
        return;
    }
    __shared__ int part[256];
    int base0 = tid * 128;
    int s = 0;
    for (int i = 0; i < 128; ++i) s += deg_i[base0 + i];
    part[tid] = s;
    __syncthreads();
    for (int off = 1; off < 256; off <<= 1) {
        int v = (tid >= off) ? part[tid - off] : 0;
        __syncthreads();
        part[tid] += v;
        __syncthreads();
    }
    int running = (tid == 0) ? 0 : part[tid - 1];
    for (int i = 0; i < 128; ++i) {
        nbase[base0 + i] = running;
        running += deg_i[base0 + i];
    }
    if (tid == 255) nbase[NTOT] = running;
}

// fill dst-CSR (XCD-swizzled: batch -> XCD, so fill2/csr_src slices are L2-local)
__global__ void k3c_fill_csr(const int* __restrict__ ei, const int* __restrict__ nbase,
                             int* fill2, int* __restrict__ csr_src) {
    int bid = blockIdx.x;
    int e = (bid & 7) * 65536 + (bid >> 3) * 256 + threadIdx.x;
    int s = ei[e], d = ei[ETOT + e];
    int slot = atomicAdd(&fill2[d], 1);
    csr_src[nbase[d] + slot] = s;
}

// fused: [0,8192) xapp gather (XCD-swizzled, bf16 src+dst, LDS-staged neighbor list)
//        [8192,8320) score gather: 1 thread = 1 node x 4 heads (int fixed-point, bit-identical)
__global__ __launch_bounds__(256) void k4_gather(const int* __restrict__ csr_src,
                                                 const int* __restrict__ nbase,
                                                 const float* __restrict__ rdeg,
                                                 const float* __restrict__ x,
                                                 const unsigned short* __restrict__ xbf,
                                                 const float* __restrict__ scores_pre,
                                                 unsigned* __restrict__ xappbf,
                                                 int* __restrict__ iscore) {
    __shared__ unsigned long long nb[4][64];               // (w_bits<<32 | s*DF)
    int bid = blockIdx.x;
    if (bid < 8192) {
        int swz = (bid & 7) * 1024 + (bid >> 3);           // batch = bid & 7 -> XCD
        int wid = threadIdx.x >> 6;
        int wv = swz * 4 + wid;                            // node id
        int lane = threadIdx.x & 63;
        float rd = rdeg[wv];
        float2 v = ((const float2*)(x + (size_t)wv * DF))[lane];   // diagonal from f32
        float acc0 = v.x * rd * rd, acc1 = v.y * rd * rd;
        int t0 = nbase[wv], t1 = nbase[wv + 1];
        int deg = t1 - t0;
        if (lane < deg && lane < 64) {
            int s = csr_src[t0 + lane];
            float w = rd * rdeg[s];
            nb[wid][lane] = ((unsigned long long)__float_as_uint(w) << 32)
                          | (unsigned)(s * DF);
        }
        int nfull = min(deg, 64);
#pragma unroll 4
        for (int t = 0; t < nfull; ++t) {
            unsigned long long e = nb[wid][t];             // uniform ds_read_b64 broadcast
            float w = __uint_as_float((unsigned)(e >> 32));
            unsigned u = ((const unsigned*)(xbf + (e & 0xFFFFFFFFu)))[lane];  // 2 bf16
            acc0 = fmaf(w, bf2f((unsigned short)(u & 0xffff)), acc0);
            acc1 = fmaf(w, bf2f((unsigned short)(u >> 16)), acc1);
        }
        for (int t = t0 + 64; t < t1; ++t) {               // tail (deg>64: ~never)
            int s = csr_src[t];
            float w = rd * rdeg[s];
            unsigned u = ((const unsigned*)(xbf + (size_t)s * DF))[lane];
            acc0 = fmaf(w, bf2f((unsigned short)(u & 0xffff)), acc0);
            acc1 = fmaf(w, bf2f((unsigned short)(u >> 16)), acc1);
        }
        xappbf[(size_t)wv * 64 + lane] =
            (unsigned)f2bf(acc0) | ((unsigned)f2bf(acc1) << 16);
    } else {
        int d = (bid - 8192) * 256 + threadIdx.x;          // node id, 32768
        float rdd = rdeg[d];
        int t0 = nbase[d], t1 = nbase[d + 1];
        int a0 = 0, a1 = 0, a2 = 0, a3 = 0;
        for (int e = t0; e < t1; ++e) {
            int s = csr_src[e];
            float w = rdeg[s] * rdd;
            float4 sp = ((const float4*)scores_pre)[s];
            a0 += __double2int_rn((double)(w * sp.x) * FP_SCALE);
            a1 += __double2int_rn((double)(w * sp.y) * FP_SCALE);
            a2 += __double2int_rn((double)(w * sp.z) * FP_SCALE);
            a3 += __double2int_rn((double)(w * sp.w) * FP_SCALE);
        }
        int4 o = {a0, a1, a2, a3};
        ((int4*)iscore)[d] = o;
    }
}

// fused: [0,512) G = concat(x,xapp)_bf16 @ W1 (MFMA) | [512,768) chunk bitonic sort.
__global__ __launch_bounds__(256) void kg5a(const unsigned short* __restrict__ xbf,
                                            const unsigned short* __restrict__ xappbf,
                                            const unsigned short* __restrict__ w1t,
                                            unsigned short* __restrict__ Gbf,
                                            const float* __restrict__ scores_pre,
                                            const int* __restrict__ iscore,
                                            const int* __restrict__ deg_i,
                                            unsigned long long* __restrict__ sorted64) {
    __shared__ __align__(16) unsigned char smem[32768];
    int bid = blockIdx.x, tid = threadIdx.x;
    if (bid < 512) {
        unsigned short* As = (unsigned short*)smem;            // [128][64] swizzled
        unsigned short* Bs = (unsigned short*)(smem + 16384);
        int m0 = (bid >> 1) * 128, n0 = (bid & 1) * 128;
        int lane = tid & 63, wid = tid >> 6;
        int wr = wid >> 1, wc = wid & 1;
        f32x4 acc[4][4];
#pragma unroll
        for (int mi = 0; mi < 4; ++mi)
#pragma unroll
            for (int ni = 0; ni < 4; ++ni) acc[mi][ni] = f32x4{0.f, 0.f, 0.f, 0.f};
        for (int kk = 0; kk < 4; ++kk) {
            int k0 = kk * 64;
            const unsigned short* Asrc = (kk < 2) ? xbf : xappbf;
            int kbase = k0 & 127;
#pragma unroll
            for (int i = 0; i < 4; ++i) {
                int gi = tid + i * 256;
                int r = gi >> 3, c = gi & 7;
                int csrc = c ^ (r & 7);
                *(bf16x8*)&As[r * 64 + c * 8] =
                    *(const bf16x8*)(Asrc + (size_t)(m0 + r) * DF + kbase + csrc * 8);
            }
#pragma unroll
            for (int i = 0; i < 4; ++i) {
                int gi = tid + i * 256;
                int r = gi >> 3, c = gi & 7;
                int csrc = c ^ (r & 7);
                *(bf16x8*)&Bs[r * 64 + c * 8] =
                    *(const bf16x8*)(w1t + (size_t)(n0 + r) * 256 + k0 + csrc * 8);
            }
            __syncthreads();
#pragma unroll
            for (int ks = 0; ks < 2; ++ks) {
                bf16x8 af[4], bfr[4];
#pragma unroll
                for (int mi = 0; mi < 4; ++mi) {
                    int r = wr * 64 + mi * 16 + (lane & 15);
                    int gl = ks * 4 + (lane >> 4);
                    af[mi] = *(const bf16x8*)&As[r * 64 + (gl ^ (r & 7)) * 8];
                }
#pragma unroll
                for (int ni = 0; ni < 4; ++ni) {
                    int r = wc * 64 + ni * 16 + (lane & 15);
                    int gl = ks * 4 + (lane >> 4);
                    bfr[ni] = *(const bf16x8*)&Bs[r * 64 + (gl ^ (r & 7)) * 8];
                }
#pragma unroll
                for (int mi = 0; mi < 4; ++mi)
#pragma unroll
                    for (int ni = 0; ni < 4; ++ni)
                        acc[mi][ni] = __builtin_amdgcn_mfma_f32_16x16x32_bf16(
                            af[mi], bfr[ni], acc[mi][ni], 0, 0, 0);
            }
            __syncthreads();
        }
#pragma unroll
        for (int mi = 0; mi < 4; ++mi) {
            int rbase = m0 + wr * 64 + mi * 16 + (lane >> 4) * 4;
#pragma unroll
            for (int ni = 0; ni < 4; ++ni) {
                int col = n0 + wc * 64 + ni * 16 + (lane & 15);
#pragma unroll
                for (int j = 0; j < 4; ++j)
                    Gbf[(size_t)(rbase + j) * DHID + col] = f2bf(acc[mi][ni][j]);
            }
        }
        return;
    }
    // ---- sort section: 512-element chunk bitonic sort ----
    unsigned long long* sk = (unsigned long long*)smem;        // 4 KB
    int blk = bid - 512;             // seg*8 + chunk
    int seg = blk >> 3, chunk = blk & 7;
    int b = seg >> 2, hh = seg & 3;
    for (int i = tid; i < 512; i += 256) {
        int p = chunk * 512 + i;
        int g = b * NN + p;
        float dg = (float)(1 + deg_i[g]);
        float sc = scores_pre[g * NH + hh] / dg + (float)((double)iscore[g * NH + hh] * FP_INV);
        sk[i] = make_key(sc, p);
    }
    __syncthreads();
    for (int size = 2; size <= 512; size <<= 1) {
        for (int stride = size >> 1; stride > 0; stride >>= 1) {
            for (int p = tid; p < 512; p += 256) {
                int q = p ^ stride;
                if (q > p) {
                    unsigned long long kp = sk[p], kq = sk[q];
                    bool before_qp = (kq < kp);
                    bool asc = ((p & size) == 0);
                    if (asc ? before_qp : !before_qp) { sk[p] = kq; sk[q] = kp; }
                }
            }
            __syncthreads();
        }
    }
    for (int i = tid; i < 512; i += 256)
        sorted64[seg * NN + chunk * 512 + i] = sk[i];
}

// sort phase B: rank via binary searches over the other 7 sorted chunks (no barriers)
__global__ __launch_bounds__(256) void k5b_rank(const unsigned long long* __restrict__ sorted64,
                                                int* __restrict__ order, int* __restrict__ pos,
                                                float* __restrict__ val) {
    int t = blockIdx.x * 256 + threadIdx.x;      // 131072
    int seg = t >> 12, i = t & 4095;
    int chunk = i >> 9, slot = i & 511;
    const unsigned long long* segp = sorted64 + (size_t)seg * NN;
    unsigned long long k = segp[chunk * 512 + slot];
    int rank = slot;
#pragma unroll
    for (int c = 0; c < 8; ++c) {
        if (c == chunk) continue;
        const unsigned long long* cp = segp + c * 512;
        int lo = 0, hi = 512;
        while (lo < hi) { int mid = (lo + hi) >> 1; lo = (cp[mid] < k) ? mid + 1 : lo; hi = (cp[mid] < k) ? hi : mid; }
        rank += lo;
    }
    int p = (int)(k & 4095u);
    pos[seg * NN + p] = rank;
    order[seg * NN + rank] = p;
    unsigned s = (unsigned)(k >> 12) ^ 0xFFFFFFFFu;
    unsigned u = s ^ (((int)s >= 0) ? 0xFFFFFFFFu : 0x80000000u);
    float sc = __uint_as_float(u);
    val[seg * NN + rank] = 1.0f / (1.0f + expf(-sc));
}

// edge binning (row == source slot; tgt eliminated)
__global__ __launch_bounds__(256) void k56_bin(const int* __restrict__ ei,
                                               const int* __restrict__ pos,
                                               int* fill, unsigned* __restrict__ elist) {
    __shared__ unsigned short pos_l[NN];      // 8 KB
    __shared__ unsigned buf[NJ][CAP_PB];      // 12 KB
    __shared__ int lcnt[NJ];
    __shared__ int gbase[NJ];
    int blkid = blockIdx.x;        // ph*8 + part
    int ph = blkid >> 3, part = blkid & 7;
    int b = ph >> 2, hh = ph & 3;
    int tid = threadIdx.x;
    for (int i = tid; i < NN; i += 256) pos_l[i] = (unsigned short)pos[ph * NN + i];
    if (tid < NJ) lcnt[tid] = 0;
    __syncthreads();
    int ebase = b * 65536 + part * 8192;
    for (int i = tid; i < 8192; i += 256) {
        int e = ebase + i;
        int s = ei[e], d = ei[ETOT + e];
        int ps = pos_l[s & 4095], pd = pos_l[d & 4095];
        if ((ps >> 7) == (pd >> 7)) {
            int blk = ps >> 7;
            int slot = atomicAdd(&lcnt[blk], 1);
            if (slot < CAP_PB)
                buf[blk][slot] = (unsigned)((ps & 127) | ((pd & 127) << 16));
        }
    }
    __syncthreads();
    if (tid < NJ) {
        int n = min(lcnt[tid], CAP_PB);
        lcnt[tid] = n;
        gbase[tid] = atomicAdd(&fill[((hh * NB + b) * NJ) + tid], n);
    }
    __syncthreads();
    for (int t = tid; t < NJ * CAP_PB; t += 256) {
        int blk = t / CAP_PB, i = t % CAP_PB;
        if (i < lcnt[blk]) {
            int g0 = gbase[blk] + i;
            if (g0 < CAP_BP) {
                int bpid = ((hh * NB + b) * NJ) + blk;
                elist[bpid * CAP_BP + g0] = buf[blk][i];
            }
        }
    }
}

// per-block: group edges by SOURCE SLOT, edge-walk column-parallel accum.
// Fused final head-mean+log_softmax via last-block pattern (device-scope fence + atomic).
__global__ __launch_bounds__(256) void k9_block(const unsigned short* __restrict__ Gbf,
                                                const int* __restrict__ order,
                                                const float* __restrict__ val,
                                                const int* __restrict__ fill,
                                                const unsigned* __restrict__ elist,
                                                const float* __restrict__ Wo,
                                                float* __restrict__ logits_bp,
                                                int* done, float* __restrict__ out) {
    __shared__ float val_s[NK];
    __shared__ int   node_s[NK];
    __shared__ int   rcnt[NK];
    __shared__ int   rend[NK];
    __shared__ int   rfill[NK];
    __shared__ unsigned el_s[CAP_BP];      // staged edge list
    __shared__ unsigned es_meta[CAP_BP];   // row<<16 | node
    __shared__ float    es_coef[CAP_BP];
    __shared__ float hvec[DHID];
    __shared__ int scan_tot;
    __shared__ int lastflag;
    int i0 = blockIdx.x;
    int xcd = i0 & 7, r0 = i0 >> 3;            // r0 in [0,128)
    int hh = r0 >> 5, blk = r0 & 31, b = xcd;  // batch -> XCD
    int bp = (hh * NB + b) * NJ + blk;
    int ph = (b << 2) | hh;
    int tid = threadIdx.x;
    if (tid < NK) {
        int p = blk * NK + tid;
        node_s[tid] = order[ph * NN + p];
        val_s[tid]  = val[ph * NN + p];
        rcnt[tid] = 0; rfill[tid] = 0;
    }
    int e0 = bp * CAP_BP;
    int ne = min(fill[bp], CAP_BP);
    for (int t = tid; t < ne; t += 256) el_s[t] = elist[e0 + t];
    __syncthreads();
    for (int t = tid; t < ne; t += 256)
        atomicAdd(&rcnt[el_s[t] & 0xffff], 1);
    __syncthreads();
    // inclusive scan of rcnt over 128 rows: shfl_up + carry
    int v = 0;
    if (tid < NK) {
        v = rcnt[tid];
        int lane = tid & 63;
#pragma unroll
        for (int off = 1; off < 64; off <<= 1) {
            int u = __shfl_up(v, off, 64);
            v += (lane >= off) ? u : 0;
        }
        if (tid == 63) scan_tot = v;
    }
    __syncthreads();
    if (tid < NK) rend[tid] = v + ((tid >= 64) ? scan_tot : 0);
    __syncthreads();
    for (int t = tid; t < ne; t += 256) {
        unsigned ent = el_s[t];
        int ss = ent & 0xffff, sd = ent >> 16;
        int slot = atomicAdd(&rfill[ss], 1);
        int p0 = rend[ss] - rcnt[ss] + slot;
        es_meta[p0] = ((unsigned)ss << 16) | (unsigned)node_s[sd];
        es_coef[p0] = val_s[ss] * val_s[sd] * val_s[sd];
    }
    __syncthreads();
    size_t gb = (size_t)b * NN * DHID + tid;
    float hsum = 0.f, m = 0.f;
    int prev = -1;
#pragma unroll 4
    for (int i = 0; i < ne; ++i) {
        unsigned md = es_meta[i];
        int row = (int)(md >> 16);
        float g = bf2f(Gbf[gb + (size_t)(md & 0xffffu) * DHID]);
        float c = es_coef[i];
        bool flush = (row != prev);
        hsum += flush ? fmaxf(m, 0.f) : 0.f;
        m = flush ? c * g : fmaf(c, g, m);
        prev = row;
    }
    hsum += fmaxf(m, 0.f);
    hvec[tid] = hsum * (1.0f / NK);
    __syncthreads();
    if (tid < NCLS) {
        float s = 0.f;
        for (int q = 0; q < DHID; ++q) s = fmaf(hvec[q], Wo[q * NCLS + tid], s);
        logits_bp[bp * NCLS + tid] = s;
    }
    // last-block: head-mean + log_softmax -> out (8,32,16)
    __threadfence();                      // release: logits visible device-wide
    __syncthreads();
    if (tid == 0) lastflag = (atomicAdd(done, 1) == BPB - 1) ? 1 : 0;
    __syncthreads();
    if (lastflag) {
        __threadfence();                  // acquire
        int t = tid;                      // 256 = 8*32
        int bb = t >> 5, bk = t & 31;
        float vv[NCLS];
#pragma unroll
        for (int c = 0; c < NCLS; ++c) {
            float s = 0.f;
#pragma unroll
            for (int h2 = 0; h2 < NH; ++h2)
                s += logits_bp[(((h2 * NB + bb) * NJ) + bk) * NCLS + c];
            vv[c] = s * 0.25f;
        }
        float mx = vv[0];
#pragma unroll
        for (int c = 1; c < NCLS; ++c) mx = fmaxf(mx, vv[c]);
        float se = 0.f;
#pragma unroll
        for (int c = 0; c < NCLS; ++c) se += expf(vv[c] - mx);
        float lse = logf(se);
#pragma unroll
        for (int c = 0; c < NCLS; ++c) out[t * NCLS + c] = vv[c] - mx - lse;
    }
}

extern "C" void kernel_launch(void* const* d_in, const int* in_sizes, int n_in,
                              void* d_out, int out_size, void* d_ws, size_t ws_size,
                              hipStream_t stream) {
    const float* x  = (const float*)d_in[0];
    const float* wr = (const float*)d_in[1];
    const float* W1 = (const float*)d_in[2];
    const float* Wo = (const float*)d_in[3];
    const int*   ei = (const int*)d_in[4];

    char* ws = (char*)d_ws;
    int*      deg_i      = (int*)(ws + 0);          // 128 KB
    float*    rdeg       = (float*)(ws + 131072);   // 128 KB
    float*    scores_pre = (float*)(ws + 262144);   // 512 KB
    int*      iscore     = (int*)(ws + 786432);     // 512 KB
    unsigned short* xbf  = (unsigned short*)(ws + 1310720);   // 8 MB
    unsigned* xappbf     = (unsigned*)(ws + 9699328);         // 8 MB (u32-packed bf16 pairs)
    unsigned short* Gbf  = (unsigned short*)(ws + 18087936);  // 16 MB
    int*      order      = (int*)(ws + 51642368);   // 512 KB
    int*      pos        = (int*)(ws + 52166656);
    float*    val        = (float*)(ws + 53215232);
    int*      fill       = (int*)(ws + 53743616);   // 4 KB (per-bpid count)
    int*      done       = (int*)(ws + 53747712);   // 4 B  (last-block counter)
    int*      csr_src    = (int*)(ws + 53755904);   // 2 MB (lifetime ends at k4)
    unsigned short* w1t  = (unsigned short*)(ws + 55853056); // 128 KB
    unsigned* elist      = (unsigned*)(ws + 53755904); // 2 MB (aliases csr_src; written at k56)
    float*    logits_bp  = (float*)(ws + 62144512); // 64 KB
    int*      nbase      = (int*)(ws + 62210048);   // 128 KB + 4
    int*      fill2      = (int*)(ws + 62341184);   // 128 KB
    unsigned long long* sorted64 = (unsigned long long*)(ws + 62472256); // 1 MB

    k0_init<<<128, 256, 0, stream>>>(deg_i, fill, fill2, done);
    k1_deg_prep<<<4480, 256, 0, stream>>>(ei, x, W1, wr, deg_i, xbf, w1t, scores_pre);
    k_prep2<<<129, 256, 0, stream>>>(deg_i, rdeg, nbase);
    k3c_fill_csr<<<2048, 256, 0, stream>>>(ei, nbase, fill2, csr_src);
    k4_gather<<<8320, 256, 0, stream>>>(csr_src, nbase, rdeg, x, xbf, scores_pre, xappbf, iscore);
    kg5a<<<768, 256, 0, stream>>>(xbf, (const unsigned short*)xappbf, w1t, Gbf,
                                  scores_pre, iscore, deg_i, sorted64);
    k5b_rank<<<512, 256, 0, stream>>>(sorted64, order, pos, val);
    k56_bin<<<256, 256, 0, stream>>>(ei, pos, fill, elist);
    k9_block<<<BPB, 256, 0, stream>>>(Gbf, order, val, fill, elist, Wo, logits_bp,
                                      done, (float*)d_out);
}

// Round 18
// 187.681 us; speedup vs baseline: 1.3226x; 1.3226x over previous
//
#include <hip/hip_runtime.h>
#include <cmath>

#define NB 8
#define NN 4096
#define DF 128
#define NH 4
#define NJ 32
#define NK 128
#define NTOT (NB*NN)          // 32768
#define ETOT 524288           // 8 * 4096 * 16
#define BPB (NH*NB*NJ)        // 1024
#define DHID 256
#define NCLS 16
#define CAP_PB 96             // per (part, blk) LDS bucket capacity (avg ~8)
#define CAP_BP 512            // per-bpid elist segment capacity (avg ~64)

#define FP_SCALE 4194304.0    // 2^22 fixed-point for deterministic score accumulation
#define FP_INV   (1.0/4194304.0)

typedef short bf16x8 __attribute__((ext_vector_type(8)));
typedef float f32x4  __attribute__((ext_vector_type(4)));

__device__ __forceinline__ unsigned short f2bf(float f) {
    unsigned u = __float_as_uint(f);
    unsigned r = (u + 0x7FFFu + ((u >> 16) & 1u)) >> 16;   // RNE
    return (unsigned short)r;
}
__device__ __forceinline__ float bf2f(unsigned short b) {
    unsigned u = ((unsigned)b) << 16;
    return __uint_as_float(u);
}

// sortable u64 key: ascending k64 == (descending score, ascending idx) — matches argsort(-s) stable
__device__ __forceinline__ unsigned long long make_key(float sc, int p) {
    unsigned u = __float_as_uint(sc);
    unsigned s = u ^ ((unsigned)((int)u >> 31) | 0x80000000u);   // ascending-float map
    return ((unsigned long long)(s ^ 0xFFFFFFFFu) << 12) | (unsigned)p;
}

// ---------------- init ----------------
__global__ void k0_init(int* deg_i, int* fill, int* fill2) {
    int t = blockIdx.x * blockDim.x + threadIdx.x;
    if (t < NTOT) { deg_i[t] = 0; fill2[t] = 0; }
    if (t < BPB) fill[t] = 0;
}

// fused: [0,2048) deg atomics (XCD-swizzled) | [2048,4096) x->bf16
//        [4096,4352) W1T | [4352,4480) scores (1 thread = 1 node x 4 heads)
__global__ __launch_bounds__(256) void k1_deg_prep(const int* __restrict__ ei,
                                                   const float* __restrict__ x,
                                                   const float* __restrict__ W1,
                                                   const float* __restrict__ wr,
                                                   int* deg_i,
                                                   unsigned short* __restrict__ xbf,
                                                   unsigned short* __restrict__ w1t,
                                                   float* __restrict__ scores_pre) {
    int bid = blockIdx.x, tid = threadIdx.x;
    if (bid < 2048) {                       // in-degree; batch = bid&7 -> same XCD L2
        int e = (bid & 7) * 65536 + (bid >> 3) * 256 + tid;
        atomicAdd(&deg_i[ei[ETOT + e]], 1);
    } else if (bid < 4096) {                // x -> bf16, 8 elems/thread
        int idx = (bid - 2048) * 256 + tid;
        const float* sp = x + (size_t)idx * 8;
        float4 lo = *(const float4*)sp;
        float4 hi = *(const float4*)(sp + 4);
        unsigned short u[8] = {f2bf(lo.x), f2bf(lo.y), f2bf(lo.z), f2bf(lo.w),
                               f2bf(hi.x), f2bf(hi.y), f2bf(hi.z), f2bf(hi.w)};
        *(bf16x8*)(xbf + (size_t)idx * 8) = *(bf16x8*)u;
    } else if (bid < 4352) {                // W1T bf16
        int t = (bid - 4096) * 256 + tid;
        int k = t >> 8, n = t & 255;
        w1t[n * 256 + k] = f2bf(W1[k * DHID + n]);
    } else {                                // scores: 1 node, 4 heads; d0-order kept per head
        int g = (bid - 4352) * 256 + tid;   // node id, 32768
        const float* xr = x + (size_t)g * DF;
        const float4* wr4 = (const float4*)wr;
        double a0 = 0.0, a1 = 0.0, a2 = 0.0, a3 = 0.0;
        for (int d0 = 0; d0 < DF; ++d0) {
            double xv = (double)xr[d0];
            float4 w = wr4[d0];
            a0 += xv * (double)w.x;
            a1 += xv * (double)w.y;
            a2 += xv * (double)w.z;
            a3 += xv * (double)w.w;
        }
        float4 o = {(float)a0, (float)a1, (float)a2, (float)a3};
        ((float4*)scores_pre)[g] = o;
    }
}

// fused: [0,128) rdeg | bid==128: exclusive deg scan (two-pass, 256 thr x 128 elems)
__global__ __launch_bounds__(256) void k_prep2(const int* __restrict__ deg_i,
                                               float* __restrict__ rdeg,
                                               int* __restrict__ nbase) {
    int bid = blockIdx.x, tid = threadIdx.x;
    if (bid < 128) {
        int t = bid * 256 + tid;
        rdeg[t] = 1.0f / sqrtf((float)(1 + deg_i[t]));
        return;
    }
    __shared__ int part[256];
    int base0 = tid * 128;
    int s = 0;
    for (int i = 0; i < 128; ++i) s += deg_i[base0 + i];
    part[tid] = s;
    __syncthreads();
    for (int off = 1; off < 256; off <<= 1) {
        int v = (tid >= off) ? part[tid - off] : 0;
        __syncthreads();
        part[tid] += v;
        __syncthreads();
    }
    int running = (tid == 0) ? 0 : part[tid - 1];
    for (int i = 0; i < 128; ++i) {
        nbase[base0 + i] = running;
        running += deg_i[base0 + i];
    }
    if (tid == 255) nbase[NTOT] = running;
}

// fill dst-CSR (XCD-swizzled: batch -> XCD, so fill2/csr_src slices are L2-local)
__global__ void k3c_fill_csr(const int* __restrict__ ei, const int* __restrict__ nbase,
                             int* fill2, int* __restrict__ csr_src) {
    int bid = blockIdx.x;
    int e = (bid & 7) * 65536 + (bid >> 3) * 256 + threadIdx.x;
    int s = ei[e], d = ei[ETOT + e];
    int slot = atomicAdd(&fill2[d], 1);
    csr_src[nbase[d] + slot] = s;
}

// fused: [0,8192) xapp gather (XCD-swizzled, bf16 src+dst, LDS-staged neighbor list)
//        [8192,8320) score gather: 1 thread = 1 node x 4 heads (int fixed-point, bit-identical)
__global__ __launch_bounds__(256) void k4_gather(const int* __restrict__ csr_src,
                                                 const int* __restrict__ nbase,
                                                 const float* __restrict__ rdeg,
                                                 const float* __restrict__ x,
                                                 const unsigned short* __restrict__ xbf,
                                                 const float* __restrict__ scores_pre,
                                                 unsigned* __restrict__ xappbf,
                                                 int* __restrict__ iscore) {
    __shared__ unsigned long long nb[4][64];               // (w_bits<<32 | s*DF)
    int bid = blockIdx.x;
    if (bid < 8192) {
        int swz = (bid & 7) * 1024 + (bid >> 3);           // batch = bid & 7 -> XCD
        int wid = threadIdx.x >> 6;
        int wv = swz * 4 + wid;                            // node id
        int lane = threadIdx.x & 63;
        float rd = rdeg[wv];
        float2 v = ((const float2*)(x + (size_t)wv * DF))[lane];   // diagonal from f32
        float acc0 = v.x * rd * rd, acc1 = v.y * rd * rd;
        int t0 = nbase[wv], t1 = nbase[wv + 1];
        int deg = t1 - t0;
        if (lane < deg && lane < 64) {
            int s = csr_src[t0 + lane];
            float w = rd * rdeg[s];
            nb[wid][lane] = ((unsigned long long)__float_as_uint(w) << 32)
                          | (unsigned)(s * DF);
        }
        int nfull = min(deg, 64);
#pragma unroll 4
        for (int t = 0; t < nfull; ++t) {
            unsigned long long e = nb[wid][t];             // uniform ds_read_b64 broadcast
            float w = __uint_as_float((unsigned)(e >> 32));
            unsigned u = ((const unsigned*)(xbf + (e & 0xFFFFFFFFu)))[lane];  // 2 bf16
            acc0 = fmaf(w, bf2f((unsigned short)(u & 0xffff)), acc0);
            acc1 = fmaf(w, bf2f((unsigned short)(u >> 16)), acc1);
        }
        for (int t = t0 + 64; t < t1; ++t) {               // tail (deg>64: ~never)
            int s = csr_src[t];
            float w = rd * rdeg[s];
            unsigned u = ((const unsigned*)(xbf + (size_t)s * DF))[lane];
            acc0 = fmaf(w, bf2f((unsigned short)(u & 0xffff)), acc0);
            acc1 = fmaf(w, bf2f((unsigned short)(u >> 16)), acc1);
        }
        xappbf[(size_t)wv * 64 + lane] =
            (unsigned)f2bf(acc0) | ((unsigned)f2bf(acc1) << 16);
    } else {
        int d = (bid - 8192) * 256 + threadIdx.x;          // node id, 32768
        float rdd = rdeg[d];
        int t0 = nbase[d], t1 = nbase[d + 1];
        int a0 = 0, a1 = 0, a2 = 0, a3 = 0;
        for (int e = t0; e < t1; ++e) {
            int s = csr_src[e];
            float w = rdeg[s] * rdd;
            float4 sp = ((const float4*)scores_pre)[s];
            a0 += __double2int_rn((double)(w * sp.x) * FP_SCALE);
            a1 += __double2int_rn((double)(w * sp.y) * FP_SCALE);
            a2 += __double2int_rn((double)(w * sp.z) * FP_SCALE);
            a3 += __double2int_rn((double)(w * sp.w) * FP_SCALE);
        }
        int4 o = {a0, a1, a2, a3};
        ((int4*)iscore)[d] = o;
    }
}

// fused: [0,512) G = concat(x,xapp)_bf16 @ W1 (MFMA) | [512,768) chunk bitonic sort.
__global__ __launch_bounds__(256) void kg5a(const unsigned short* __restrict__ xbf,
                                            const unsigned short* __restrict__ xappbf,
                                            const unsigned short* __restrict__ w1t,
                                            unsigned short* __restrict__ Gbf,
                                            const float* __restrict__ scores_pre,
                                            const int* __restrict__ iscore,
                                            const int* __restrict__ deg_i,
                                            unsigned long long* __restrict__ sorted64) {
    __shared__ __align__(16) unsigned char smem[32768];
    int bid = blockIdx.x, tid = threadIdx.x;
    if (bid < 512) {
        unsigned short* As = (unsigned short*)smem;            // [128][64] swizzled
        unsigned short* Bs = (unsigned short*)(smem + 16384);
        int m0 = (bid >> 1) * 128, n0 = (bid & 1) * 128;
        int lane = tid & 63, wid = tid >> 6;
        int wr = wid >> 1, wc = wid & 1;
        f32x4 acc[4][4];
#pragma unroll
        for (int mi = 0; mi < 4; ++mi)
#pragma unroll
            for (int ni = 0; ni < 4; ++ni) acc[mi][ni] = f32x4{0.f, 0.f, 0.f, 0.f};
        for (int kk = 0; kk < 4; ++kk) {
            int k0 = kk * 64;
            const unsigned short* Asrc = (kk < 2) ? xbf : xappbf;
            int kbase = k0 & 127;
#pragma unroll
            for (int i = 0; i < 4; ++i) {
                int gi = tid + i * 256;
                int r = gi >> 3, c = gi & 7;
                int csrc = c ^ (r & 7);
                *(bf16x8*)&As[r * 64 + c * 8] =
                    *(const bf16x8*)(Asrc + (size_t)(m0 + r) * DF + kbase + csrc * 8);
            }
#pragma unroll
            for (int i = 0; i < 4; ++i) {
                int gi = tid + i * 256;
                int r = gi >> 3, c = gi & 7;
                int csrc = c ^ (r & 7);
                *(bf16x8*)&Bs[r * 64 + c * 8] =
                    *(const bf16x8*)(w1t + (size_t)(n0 + r) * 256 + k0 + csrc * 8);
            }
            __syncthreads();
#pragma unroll
            for (int ks = 0; ks < 2; ++ks) {
                bf16x8 af[4], bfr[4];
#pragma unroll
                for (int mi = 0; mi < 4; ++mi) {
                    int r = wr * 64 + mi * 16 + (lane & 15);
                    int gl = ks * 4 + (lane >> 4);
                    af[mi] = *(const bf16x8*)&As[r * 64 + (gl ^ (r & 7)) * 8];
                }
#pragma unroll
                for (int ni = 0; ni < 4; ++ni) {
                    int r = wc * 64 + ni * 16 + (lane & 15);
                    int gl = ks * 4 + (lane >> 4);
                    bfr[ni] = *(const bf16x8*)&Bs[r * 64 + (gl ^ (r & 7)) * 8];
                }
#pragma unroll
                for (int mi = 0; mi < 4; ++mi)
#pragma unroll
                    for (int ni = 0; ni < 4; ++ni)
                        acc[mi][ni] = __builtin_amdgcn_mfma_f32_16x16x32_bf16(
                            af[mi], bfr[ni], acc[mi][ni], 0, 0, 0);
            }
            __syncthreads();
        }
#pragma unroll
        for (int mi = 0; mi < 4; ++mi) {
            int rbase = m0 + wr * 64 + mi * 16 + (lane >> 4) * 4;
#pragma unroll
            for (int ni = 0; ni < 4; ++ni) {
                int col = n0 + wc * 64 + ni * 16 + (lane & 15);
#pragma unroll
                for (int j = 0; j < 4; ++j)
                    Gbf[(size_t)(rbase + j) * DHID + col] = f2bf(acc[mi][ni][j]);
            }
        }
        return;
    }
    // ---- sort section: 512-element chunk bitonic sort ----
    unsigned long long* sk = (unsigned long long*)smem;        // 4 KB
    int blk = bid - 512;             // seg*8 + chunk
    int seg = blk >> 3, chunk = blk & 7;
    int b = seg >> 2, hh = seg & 3;
    for (int i = tid; i < 512; i += 256) {
        int p = chunk * 512 + i;
        int g = b * NN + p;
        float dg = (float)(1 + deg_i[g]);
        float sc = scores_pre[g * NH + hh] / dg + (float)((double)iscore[g * NH + hh] * FP_INV);
        sk[i] = make_key(sc, p);
    }
    __syncthreads();
    for (int size = 2; size <= 512; size <<= 1) {
        for (int stride = size >> 1; stride > 0; stride >>= 1) {
            for (int p = tid; p < 512; p += 256) {
                int q = p ^ stride;
                if (q > p) {
                    unsigned long long kp = sk[p], kq = sk[q];
                    bool before_qp = (kq < kp);
                    bool asc = ((p & size) == 0);
                    if (asc ? before_qp : !before_qp) { sk[p] = kq; sk[q] = kp; }
                }
            }
            __syncthreads();
        }
    }
    for (int i = tid; i < 512; i += 256)
        sorted64[seg * NN + chunk * 512 + i] = sk[i];
}

// sort phase B: rank via binary searches over the other 7 sorted chunks (no barriers)
__global__ __launch_bounds__(256) void k5b_rank(const unsigned long long* __restrict__ sorted64,
                                                int* __restrict__ order, int* __restrict__ pos,
                                                float* __restrict__ val) {
    int t = blockIdx.x * 256 + threadIdx.x;      // 131072
    int seg = t >> 12, i = t & 4095;
    int chunk = i >> 9, slot = i & 511;
    const unsigned long long* segp = sorted64 + (size_t)seg * NN;
    unsigned long long k = segp[chunk * 512 + slot];
    int rank = slot;
#pragma unroll
    for (int c = 0; c < 8; ++c) {
        if (c == chunk) continue;
        const unsigned long long* cp = segp + c * 512;
        int lo = 0, hi = 512;
        while (lo < hi) { int mid = (lo + hi) >> 1; lo = (cp[mid] < k) ? mid + 1 : lo; hi = (cp[mid] < k) ? hi : mid; }
        rank += lo;
    }
    int p = (int)(k & 4095u);
    pos[seg * NN + p] = rank;
    order[seg * NN + rank] = p;
    unsigned s = (unsigned)(k >> 12) ^ 0xFFFFFFFFu;
    unsigned u = s ^ (((int)s >= 0) ? 0xFFFFFFFFu : 0x80000000u);
    float sc = __uint_as_float(u);
    val[seg * NN + rank] = 1.0f / (1.0f + expf(-sc));
}

// edge binning (row == source slot; tgt eliminated)
__global__ __launch_bounds__(256) void k56_bin(const int* __restrict__ ei,
                                               const int* __restrict__ pos,
                                               int* fill, unsigned* __restrict__ elist) {
    __shared__ unsigned short pos_l[NN];      // 8 KB
    __shared__ unsigned buf[NJ][CAP_PB];      // 12 KB
    __shared__ int lcnt[NJ];
    __shared__ int gbase[NJ];
    int blkid = blockIdx.x;        // ph*8 + part
    int ph = blkid >> 3, part = blkid & 7;
    int b = ph >> 2, hh = ph & 3;
    int tid = threadIdx.x;
    for (int i = tid; i < NN; i += 256) pos_l[i] = (unsigned short)pos[ph * NN + i];
    if (tid < NJ) lcnt[tid] = 0;
    __syncthreads();
    int ebase = b * 65536 + part * 8192;
    for (int i = tid; i < 8192; i += 256) {
        int e = ebase + i;
        int s = ei[e], d = ei[ETOT + e];
        int ps = pos_l[s & 4095], pd = pos_l[d & 4095];
        if ((ps >> 7) == (pd >> 7)) {
            int blk = ps >> 7;
            int slot = atomicAdd(&lcnt[blk], 1);
            if (slot < CAP_PB)
                buf[blk][slot] = (unsigned)((ps & 127) | ((pd & 127) << 16));
        }
    }
    __syncthreads();
    if (tid < NJ) {
        int n = min(lcnt[tid], CAP_PB);
        lcnt[tid] = n;
        gbase[tid] = atomicAdd(&fill[((hh * NB + b) * NJ) + tid], n);
    }
    __syncthreads();
    for (int t = tid; t < NJ * CAP_PB; t += 256) {
        int blk = t / CAP_PB, i = t % CAP_PB;
        if (i < lcnt[blk]) {
            int g0 = gbase[blk] + i;
            if (g0 < CAP_BP) {
                int bpid = ((hh * NB + b) * NJ) + blk;
                elist[bpid * CAP_BP + g0] = buf[blk][i];
            }
        }
    }
}

// per-block: group edges by SOURCE SLOT, edge-walk column-parallel accum (no fence/fusion)
__global__ __launch_bounds__(256) void k9_block(const unsigned short* __restrict__ Gbf,
                                                const int* __restrict__ order,
                                                const float* __restrict__ val,
                                                const int* __restrict__ fill,
                                                const unsigned* __restrict__ elist,
                                                const float* __restrict__ Wo,
                                                float* __restrict__ logits_bp) {
    __shared__ float val_s[NK];
    __shared__ int   node_s[NK];
    __shared__ int   rcnt[NK];
    __shared__ int   rend[NK];
    __shared__ int   rfill[NK];
    __shared__ unsigned el_s[CAP_BP];      // staged edge list
    __shared__ unsigned es_meta[CAP_BP];   // row<<16 | node
    __shared__ float    es_coef[CAP_BP];
    __shared__ float hvec[DHID];
    __shared__ int scan_tot;
    int i0 = blockIdx.x;
    int xcd = i0 & 7, r0 = i0 >> 3;            // r0 in [0,128)
    int hh = r0 >> 5, blk = r0 & 31, b = xcd;  // batch -> XCD
    int bp = (hh * NB + b) * NJ + blk;
    int ph = (b << 2) | hh;
    int tid = threadIdx.x;
    if (tid < NK) {
        int p = blk * NK + tid;
        node_s[tid] = order[ph * NN + p];
        val_s[tid]  = val[ph * NN + p];
        rcnt[tid] = 0; rfill[tid] = 0;
    }
    int e0 = bp * CAP_BP;
    int ne = min(fill[bp], CAP_BP);
    for (int t = tid; t < ne; t += 256) el_s[t] = elist[e0 + t];
    __syncthreads();
    for (int t = tid; t < ne; t += 256)
        atomicAdd(&rcnt[el_s[t] & 0xffff], 1);
    __syncthreads();
    // inclusive scan of rcnt over 128 rows: shfl_up + carry
    int v = 0;
    if (tid < NK) {
        v = rcnt[tid];
        int lane = tid & 63;
#pragma unroll
        for (int off = 1; off < 64; off <<= 1) {
            int u = __shfl_up(v, off, 64);
            v += (lane >= off) ? u : 0;
        }
        if (tid == 63) scan_tot = v;
    }
    __syncthreads();
    if (tid < NK) rend[tid] = v + ((tid >= 64) ? scan_tot : 0);
    __syncthreads();
    for (int t = tid; t < ne; t += 256) {
        unsigned ent = el_s[t];
        int ss = ent & 0xffff, sd = ent >> 16;
        int slot = atomicAdd(&rfill[ss], 1);
        int p0 = rend[ss] - rcnt[ss] + slot;
        es_meta[p0] = ((unsigned)ss << 16) | (unsigned)node_s[sd];
        es_coef[p0] = val_s[ss] * val_s[sd] * val_s[sd];
    }
    __syncthreads();
    size_t gb = (size_t)b * NN * DHID + tid;
    float hsum = 0.f, m = 0.f;
    int prev = -1;
#pragma unroll 4
    for (int i = 0; i < ne; ++i) {
        unsigned md = es_meta[i];
        int row = (int)(md >> 16);
        float g = bf2f(Gbf[gb + (size_t)(md & 0xffffu) * DHID]);
        float c = es_coef[i];
        bool flush = (row != prev);
        hsum += flush ? fmaxf(m, 0.f) : 0.f;
        m = flush ? c * g : fmaf(c, g, m);
        prev = row;
    }
    hsum += fmaxf(m, 0.f);
    hvec[tid] = hsum * (1.0f / NK);
    __syncthreads();
    if (tid < NCLS) {
        float s = 0.f;
        for (int q = 0; q < DHID; ++q) s = fmaf(hvec[q], Wo[q * NCLS + tid], s);
        logits_bp[bp * NCLS + tid] = s;
    }
}

// head-mean + log_softmax -> (8,32,16)
__global__ void k10_final(const float* __restrict__ logits_bp, float* __restrict__ out) {
    int t = threadIdx.x;                 // 256 = 8*32
    int b = t >> 5, blk = t & 31;
    float v[NCLS];
#pragma unroll
    for (int c = 0; c < NCLS; ++c) {
        float s = 0.f;
        for (int hh = 0; hh < NH; ++hh)
            s += logits_bp[(((hh * NB + b) * NJ) + blk) * NCLS + c];
        v[c] = s * 0.25f;
    }
    float mx = v[0];
#pragma unroll
    for (int c = 1; c < NCLS; ++c) mx = fmaxf(mx, v[c]);
    float se = 0.f;
#pragma unroll
    for (int c = 0; c < NCLS; ++c) se += expf(v[c] - mx);
    float lse = logf(se);
#pragma unroll
    for (int c = 0; c < NCLS; ++c) out[t * NCLS + c] = v[c] - mx - lse;
}

extern "C" void kernel_launch(void* const* d_in, const int* in_sizes, int n_in,
                              void* d_out, int out_size, void* d_ws, size_t ws_size,
                              hipStream_t stream) {
    const float* x  = (const float*)d_in[0];
    const float* wr = (const float*)d_in[1];
    const float* W1 = (const float*)d_in[2];
    const float* Wo = (const float*)d_in[3];
    const int*   ei = (const int*)d_in[4];

    char* ws = (char*)d_ws;
    int*      deg_i      = (int*)(ws + 0);          // 128 KB
    float*    rdeg       = (float*)(ws + 131072);   // 128 KB
    float*    scores_pre = (float*)(ws + 262144);   // 512 KB
    int*      iscore     = (int*)(ws + 786432);     // 512 KB
    unsigned short* xbf  = (unsigned short*)(ws + 1310720);   // 8 MB
    unsigned* xappbf     = (unsigned*)(ws + 9699328);         // 8 MB (u32-packed bf16 pairs)
    unsigned short* Gbf  = (unsigned short*)(ws + 18087936);  // 16 MB
    int*      order      = (int*)(ws + 51642368);   // 512 KB
    int*      pos        = (int*)(ws + 52166656);
    float*    val        = (float*)(ws + 53215232);
    int*      fill       = (int*)(ws + 53743616);   // 4 KB (per-bpid count)
    int*      csr_src    = (int*)(ws + 53755904);   // 2 MB (lifetime ends at k4)
    unsigned short* w1t  = (unsigned short*)(ws + 55853056); // 128 KB
    unsigned* elist      = (unsigned*)(ws + 53755904); // 2 MB (aliases csr_src; written at k56)
    float*    logits_bp  = (float*)(ws + 62144512); // 64 KB
    int*      nbase      = (int*)(ws + 62210048);   // 128 KB + 4
    int*      fill2      = (int*)(ws + 62341184);   // 128 KB
    unsigned long long* sorted64 = (unsigned long long*)(ws + 62472256); // 1 MB

    k0_init<<<128, 256, 0, stream>>>(deg_i, fill, fill2);
    k1_deg_prep<<<4480, 256, 0, stream>>>(ei, x, W1, wr, deg_i, xbf, w1t, scores_pre);
    k_prep2<<<129, 256, 0, stream>>>(deg_i, rdeg, nbase);
    k3c_fill_csr<<<2048, 256, 0, stream>>>(ei, nbase, fill2, csr_src);
    k4_gather<<<8320, 256, 0, stream>>>(csr_src, nbase, rdeg, x, xbf, scores_pre, xappbf, iscore);
    kg5a<<<768, 256, 0, stream>>>(xbf, (const unsigned short*)xappbf, w1t, Gbf,
                                  scores_pre, iscore, deg_i, sorted64);
    k5b_rank<<<512, 256, 0, stream>>>(sorted64, order, pos, val);
    k56_bin<<<256, 256, 0, stream>>>(ei, pos, fill, elist);
    k9_block<<<BPB, 256, 0, stream>>>(Gbf, order, val, fill, elist, Wo, logits_bp);
    k10_final<<<1, 256, 0, stream>>>(logits_bp, (float*)d_out);
}

// Round 19
// 174.126 us; speedup vs baseline: 1.4256x; 1.0778x over previous
//
#include <hip/hip_runtime.h>
#include <cmath>

#define NB 8
#define NN 4096
#define DF 128
#define NH 4
#define NJ 32
#define NK 128
#define NTOT (NB*NN)          // 32768
#define ETOT 524288           // 8 * 4096 * 16
#define BPB (NH*NB*NJ)        // 1024
#define DHID 256
#define NCLS 16
#define CAP_PB 96             // per (part, blk) LDS bucket capacity (avg ~8)
#define CAP_BP 512            // per-bpid elist segment capacity (avg ~64)

#define FP_SCALE 4194304.0    // 2^22 fixed-point for deterministic score accumulation
#define FP_INV   (1.0/4194304.0)

typedef short bf16x8 __attribute__((ext_vector_type(8)));
typedef float f32x4  __attribute__((ext_vector_type(4)));

__device__ __forceinline__ unsigned short f2bf(float f) {
    unsigned u = __float_as_uint(f);
    unsigned r = (u + 0x7FFFu + ((u >> 16) & 1u)) >> 16;   // RNE
    return (unsigned short)r;
}
__device__ __forceinline__ float bf2f(unsigned short b) {
    unsigned u = ((unsigned)b) << 16;
    return __uint_as_float(u);
}

// sortable u64 key: ascending k64 == (descending score, ascending idx) — matches argsort(-s) stable
__device__ __forceinline__ unsigned long long make_key(float sc, int p) {
    unsigned u = __float_as_uint(sc);
    unsigned s = u ^ ((unsigned)((int)u >> 31) | 0x80000000u);   // ascending-float map
    return ((unsigned long long)(s ^ 0xFFFFFFFFu) << 12) | (unsigned)p;
}

// ---------------- init ----------------
__global__ void k0_init(int* deg_i, int* fill, int* fill2) {
    int t = blockIdx.x * blockDim.x + threadIdx.x;
    if (t < NTOT) { deg_i[t] = 0; fill2[t] = 0; }
    if (t < BPB) fill[t] = 0;
}

// fused: [0,2048) deg atomics (XCD-swizzled) | [2048,4096) x->bf16
//        [4096,4352) W1T | [4352,4864) scores (per (node,head): latency-bound -> max threads)
__global__ __launch_bounds__(256) void k1_deg_prep(const int* __restrict__ ei,
                                                   const float* __restrict__ x,
                                                   const float* __restrict__ W1,
                                                   const float* __restrict__ wr,
                                                   int* deg_i,
                                                   unsigned short* __restrict__ xbf,
                                                   unsigned short* __restrict__ w1t,
                                                   float* __restrict__ scores_pre) {
    int bid = blockIdx.x, tid = threadIdx.x;
    if (bid < 2048) {                       // in-degree; batch = bid&7 -> same XCD L2
        int e = (bid & 7) * 65536 + (bid >> 3) * 256 + tid;
        atomicAdd(&deg_i[ei[ETOT + e]], 1);
    } else if (bid < 4096) {                // x -> bf16, 8 elems/thread
        int idx = (bid - 2048) * 256 + tid;
        const float* sp = x + (size_t)idx * 8;
        float4 lo = *(const float4*)sp;
        float4 hi = *(const float4*)(sp + 4);
        unsigned short u[8] = {f2bf(lo.x), f2bf(lo.y), f2bf(lo.z), f2bf(lo.w),
                               f2bf(hi.x), f2bf(hi.y), f2bf(hi.z), f2bf(hi.w)};
        *(bf16x8*)(xbf + (size_t)idx * 8) = *(bf16x8*)u;
    } else if (bid < 4352) {                // W1T bf16
        int t = (bid - 4096) * 256 + tid;
        int k = t >> 8, n = t & 255;
        w1t[n * 256 + k] = f2bf(W1[k * DHID + n]);
    } else {                                // scores_pre = x @ W_rank (double accum)
        int t = (bid - 4352) * 256 + tid;
        int g = t >> 2, hh = t & 3;
        const float* xr = x + (size_t)g * DF;
        double acc = 0.0;
        for (int d0 = 0; d0 < DF; ++d0) acc += (double)xr[d0] * (double)wr[d0 * NH + hh];
        scores_pre[t] = (float)acc;
    }
}

// fused: [0,128) rdeg | bid==128: exclusive deg scan (two-pass, 256 thr x 128 elems)
__global__ __launch_bounds__(256) void k_prep2(const int* __restrict__ deg_i,
                                               float* __restrict__ rdeg,
                                               int* __restrict__ nbase) {
    int bid = blockIdx.x, tid = threadIdx.x;
    if (bid < 128) {
        int t = bid * 256 + tid;
        rdeg[t] = 1.0f / sqrtf((float)(1 + deg_i[t]));
        return;
    }
    __shared__ int part[256];
    int base0 = tid * 128;
    int s = 0;
    for (int i = 0; i < 128; ++i) s += deg_i[base0 + i];
    part[tid] = s;
    __syncthreads();
    for (int off = 1; off < 256; off <<= 1) {
        int v = (tid >= off) ? part[tid - off] : 0;
        __syncthreads();
        part[tid] += v;
        __syncthreads();
    }
    int running = (tid == 0) ? 0 : part[tid - 1];
    for (int i = 0; i < 128; ++i) {
        nbase[base0 + i] = running;
        running += deg_i[base0 + i];
    }
    if (tid == 255) nbase[NTOT] = running;
}

// fill dst-CSR (XCD-swizzled: batch -> XCD, so fill2/csr_src slices are L2-local)
__global__ void k3c_fill_csr(const int* __restrict__ ei, const int* __restrict__ nbase,
                             int* fill2, int* __restrict__ csr_src) {
    int bid = blockIdx.x;
    int e = (bid & 7) * 65536 + (bid >> 3) * 256 + threadIdx.x;
    int s = ei[e], d = ei[ETOT + e];
    int slot = atomicAdd(&fill2[d], 1);
    csr_src[nbase[d] + slot] = s;
}

// fused: [0,8192) xapp gather (XCD-swizzled, bf16 src+dst, LDS-staged neighbor list)
//        [8192,8704) score gather per (node,head) (int fixed-point, deterministic)
__global__ __launch_bounds__(256) void k4_gather(const int* __restrict__ csr_src,
                                                 const int* __restrict__ nbase,
                                                 const float* __restrict__ rdeg,
                                                 const float* __restrict__ x,
                                                 const unsigned short* __restrict__ xbf,
                                                 const float* __restrict__ scores_pre,
                                                 unsigned* __restrict__ xappbf,
                                                 int* __restrict__ iscore) {
    __shared__ unsigned long long nb[4][64];               // (w_bits<<32 | s*DF)
    int bid = blockIdx.x;
    if (bid < 8192) {
        int swz = (bid & 7) * 1024 + (bid >> 3);           // batch = bid & 7 -> XCD
        int wid = threadIdx.x >> 6;
        int wv = swz * 4 + wid;                            // node id
        int lane = threadIdx.x & 63;
        float rd = rdeg[wv];
        float2 v = ((const float2*)(x + (size_t)wv * DF))[lane];   // diagonal from f32
        float acc0 = v.x * rd * rd, acc1 = v.y * rd * rd;
        int t0 = nbase[wv], t1 = nbase[wv + 1];
        int deg = t1 - t0;
        if (lane < deg && lane < 64) {
            int s = csr_src[t0 + lane];
            float w = rd * rdeg[s];
            nb[wid][lane] = ((unsigned long long)__float_as_uint(w) << 32)
                          | (unsigned)(s * DF);
        }
        int nfull = min(deg, 64);
#pragma unroll 4
        for (int t = 0; t < nfull; ++t) {
            unsigned long long e = nb[wid][t];             // uniform ds_read_b64 broadcast
            float w = __uint_as_float((unsigned)(e >> 32));
            unsigned u = ((const unsigned*)(xbf + (e & 0xFFFFFFFFu)))[lane];  // 2 bf16
            acc0 = fmaf(w, bf2f((unsigned short)(u & 0xffff)), acc0);
            acc1 = fmaf(w, bf2f((unsigned short)(u >> 16)), acc1);
        }
        for (int t = t0 + 64; t < t1; ++t) {               // tail (deg>64: ~never)
            int s = csr_src[t];
            float w = rd * rdeg[s];
            unsigned u = ((const unsigned*)(xbf + (size_t)s * DF))[lane];
            acc0 = fmaf(w, bf2f((unsigned short)(u & 0xffff)), acc0);
            acc1 = fmaf(w, bf2f((unsigned short)(u >> 16)), acc1);
        }
        xappbf[(size_t)wv * 64 + lane] =
            (unsigned)f2bf(acc0) | ((unsigned)f2bf(acc1) << 16);
    } else {
        int t = (bid - 8192) * 256 + threadIdx.x;          // node*4 + hh
        int d = t >> 2, hh = t & 3;
        float rdd = rdeg[d];
        int t0 = nbase[d], t1 = nbase[d + 1];
        int acc = 0;
        for (int e = t0; e < t1; ++e) {
            int s = csr_src[e];
            float w = rdeg[s] * rdd;
            double term = (double)(w * scores_pre[s * NH + hh]);
            acc += __double2int_rn(term * FP_SCALE);
        }
        iscore[t] = acc;
    }
}

// fused: [0,512) G = concat(x,xapp)_bf16 @ W1 (MFMA) | [512,768) chunk bitonic sort.
__global__ __launch_bounds__(256) void kg5a(const unsigned short* __restrict__ xbf,
                                            const unsigned short* __restrict__ xappbf,
                                            const unsigned short* __restrict__ w1t,
                                            unsigned short* __restrict__ Gbf,
                                            const float* __restrict__ scores_pre,
                                            const int* __restrict__ iscore,
                                            const int* __restrict__ deg_i,
                                            unsigned long long* __restrict__ sorted64) {
    __shared__ __align__(16) unsigned char smem[32768];
    int bid = blockIdx.x, tid = threadIdx.x;
    if (bid < 512) {
        unsigned short* As = (unsigned short*)smem;            // [128][64] swizzled
        unsigned short* Bs = (unsigned short*)(smem + 16384);
        int m0 = (bid >> 1) * 128, n0 = (bid & 1) * 128;
        int lane = tid & 63, wid = tid >> 6;
        int wr = wid >> 1, wc = wid & 1;
        f32x4 acc[4][4];
#pragma unroll
        for (int mi = 0; mi < 4; ++mi)
#pragma unroll
            for (int ni = 0; ni < 4; ++ni) acc[mi][ni] = f32x4{0.f, 0.f, 0.f, 0.f};
        for (int kk = 0; kk < 4; ++kk) {
            int k0 = kk * 64;
            const unsigned short* Asrc = (kk < 2) ? xbf : xappbf;
            int kbase = k0 & 127;
#pragma unroll
            for (int i = 0; i < 4; ++i) {
                int gi = tid + i * 256;
                int r = gi >> 3, c = gi & 7;
                int csrc = c ^ (r & 7);
                *(bf16x8*)&As[r * 64 + c * 8] =
                    *(const bf16x8*)(Asrc + (size_t)(m0 + r) * DF + kbase + csrc * 8);
            }
#pragma unroll
            for (int i = 0; i < 4; ++i) {
                int gi = tid + i * 256;
                int r = gi >> 3, c = gi & 7;
                int csrc = c ^ (r & 7);
                *(bf16x8*)&Bs[r * 64 + c * 8] =
                    *(const bf16x8*)(w1t + (size_t)(n0 + r) * 256 + k0 + csrc * 8);
            }
            __syncthreads();
#pragma unroll
            for (int ks = 0; ks < 2; ++ks) {
                bf16x8 af[4], bfr[4];
#pragma unroll
                for (int mi = 0; mi < 4; ++mi) {
                    int r = wr * 64 + mi * 16 + (lane & 15);
                    int gl = ks * 4 + (lane >> 4);
                    af[mi] = *(const bf16x8*)&As[r * 64 + (gl ^ (r & 7)) * 8];
                }
#pragma unroll
                for (int ni = 0; ni < 4; ++ni) {
                    int r = wc * 64 + ni * 16 + (lane & 15);
                    int gl = ks * 4 + (lane >> 4);
                    bfr[ni] = *(const bf16x8*)&Bs[r * 64 + (gl ^ (r & 7)) * 8];
                }
#pragma unroll
                for (int mi = 0; mi < 4; ++mi)
#pragma unroll
                    for (int ni = 0; ni < 4; ++ni)
                        acc[mi][ni] = __builtin_amdgcn_mfma_f32_16x16x32_bf16(
                            af[mi], bfr[ni], acc[mi][ni], 0, 0, 0);
            }
            __syncthreads();
        }
#pragma unroll
        for (int mi = 0; mi < 4; ++mi) {
            int rbase = m0 + wr * 64 + mi * 16 + (lane >> 4) * 4;
#pragma unroll
            for (int ni = 0; ni < 4; ++ni) {
                int col = n0 + wc * 64 + ni * 16 + (lane & 15);
#pragma unroll
                for (int j = 0; j < 4; ++j)
                    Gbf[(size_t)(rbase + j) * DHID + col] = f2bf(acc[mi][ni][j]);
            }
        }
        return;
    }
    // ---- sort section: 512-element chunk bitonic sort ----
    unsigned long long* sk = (unsigned long long*)smem;        // 4 KB
    int blk = bid - 512;             // seg*8 + chunk
    int seg = blk >> 3, chunk = blk & 7;
    int b = seg >> 2, hh = seg & 3;
    for (int i = tid; i < 512; i += 256) {
        int p = chunk * 512 + i;
        int g = b * NN + p;
        float dg = (float)(1 + deg_i[g]);
        float sc = scores_pre[g * NH + hh] / dg + (float)((double)iscore[g * NH + hh] * FP_INV);
        sk[i] = make_key(sc, p);
    }
    __syncthreads();
    for (int size = 2; size <= 512; size <<= 1) {
        for (int stride = size >> 1; stride > 0; stride >>= 1) {
            for (int p = tid; p < 512; p += 256) {
                int q = p ^ stride;
                if (q > p) {
                    unsigned long long kp = sk[p], kq = sk[q];
                    bool before_qp = (kq < kp);
                    bool asc = ((p & size) == 0);
                    if (asc ? before_qp : !before_qp) { sk[p] = kq; sk[q] = kp; }
                }
            }
            __syncthreads();
        }
    }
    for (int i = tid; i < 512; i += 256)
        sorted64[seg * NN + chunk * 512 + i] = sk[i];
}

// sort phase B: LDS-staged segment, rank via binary searches in LDS (bit-identical outputs)
__global__ __launch_bounds__(256) void k5b_rank(const unsigned long long* __restrict__ sorted64,
                                                int* __restrict__ order, int* __restrict__ pos,
                                                float* __restrict__ val) {
    __shared__ unsigned long long seg_l[NN];     // 32 KB: whole segment
    int bid = blockIdx.x;                        // 512; 16 blocks per segment
    int seg = bid >> 4;
    const unsigned long long* segp = sorted64 + (size_t)seg * NN;
    for (int i = threadIdx.x; i < NN; i += 256)
        seg_l[i] = segp[i];
    __syncthreads();
    int i = (bid & 15) * 256 + threadIdx.x;      // element within segment
    int chunk = i >> 9, slot = i & 511;
    unsigned long long k = seg_l[chunk * 512 + slot];
    int rank = slot;
#pragma unroll
    for (int c = 0; c < 8; ++c) {
        if (c == chunk) continue;
        const unsigned long long* cp = seg_l + c * 512;
        int lo = 0, hi = 512;
        while (lo < hi) { int mid = (lo + hi) >> 1; lo = (cp[mid] < k) ? mid + 1 : lo; hi = (cp[mid] < k) ? hi : mid; }
        rank += lo;
    }
    int p = (int)(k & 4095u);
    pos[seg * NN + p] = rank;
    order[seg * NN + rank] = p;
    unsigned s = (unsigned)(k >> 12) ^ 0xFFFFFFFFu;
    unsigned u = s ^ (((int)s >= 0) ? 0xFFFFFFFFu : 0x80000000u);
    float sc = __uint_as_float(u);
    val[seg * NN + rank] = 1.0f / (1.0f + expf(-sc));
}

// edge binning (row == source slot; tgt eliminated)
__global__ __launch_bounds__(256) void k56_bin(const int* __restrict__ ei,
                                               const int* __restrict__ pos,
                                               int* fill, unsigned* __restrict__ elist) {
    __shared__ unsigned short pos_l[NN];      // 8 KB
    __shared__ unsigned buf[NJ][CAP_PB];      // 12 KB
    __shared__ int lcnt[NJ];
    __shared__ int gbase[NJ];
    int blkid = blockIdx.x;        // ph*8 + part
    int ph = blkid >> 3, part = blkid & 7;
    int b = ph >> 2, hh = ph & 3;
    int tid = threadIdx.x;
    for (int i = tid; i < NN; i += 256) pos_l[i] = (unsigned short)pos[ph * NN + i];
    if (tid < NJ) lcnt[tid] = 0;
    __syncthreads();
    int ebase = b * 65536 + part * 8192;
    for (int i = tid; i < 8192; i += 256) {
        int e = ebase + i;
        int s = ei[e], d = ei[ETOT + e];
        int ps = pos_l[s & 4095], pd = pos_l[d & 4095];
        if ((ps >> 7) == (pd >> 7)) {
            int blk = ps >> 7;
            int slot = atomicAdd(&lcnt[blk], 1);
            if (slot < CAP_PB)
                buf[blk][slot] = (unsigned)((ps & 127) | ((pd & 127) << 16));
        }
    }
    __syncthreads();
    if (tid < NJ) {
        int n = min(lcnt[tid], CAP_PB);
        lcnt[tid] = n;
        gbase[tid] = atomicAdd(&fill[((hh * NB + b) * NJ) + tid], n);
    }
    __syncthreads();
    for (int t = tid; t < NJ * CAP_PB; t += 256) {
        int blk = t / CAP_PB, i = t % CAP_PB;
        if (i < lcnt[blk]) {
            int g0 = gbase[blk] + i;
            if (g0 < CAP_BP) {
                int bpid = ((hh * NB + b) * NJ) + blk;
                elist[bpid * CAP_BP + g0] = buf[blk][i];
            }
        }
    }
}

// per-block: group edges by SOURCE SLOT, edge-walk column-parallel accum
__global__ __launch_bounds__(256) void k9_block(const unsigned short* __restrict__ Gbf,
                                                const int* __restrict__ order,
                                                const float* __restrict__ val,
                                                const int* __restrict__ fill,
                                                const unsigned* __restrict__ elist,
                                                const float* __restrict__ Wo,
                                                float* __restrict__ logits_bp) {
    __shared__ float val_s[NK];
    __shared__ int   node_s[NK];
    __shared__ int   rcnt[NK];
    __shared__ int   rend[NK];
    __shared__ int   rfill[NK];
    __shared__ unsigned el_s[CAP_BP];      // staged edge list
    __shared__ unsigned es_meta[CAP_BP];   // row<<16 | node
    __shared__ float    es_coef[CAP_BP];
    __shared__ float hvec[DHID];
    __shared__ int scan_tot;
    int i0 = blockIdx.x;
    int xcd = i0 & 7, r0 = i0 >> 3;            // r0 in [0,128)
    int hh = r0 >> 5, blk = r0 & 31, b = xcd;  // batch -> XCD
    int bp = (hh * NB + b) * NJ + blk;
    int ph = (b << 2) | hh;
    int tid = threadIdx.x;
    if (tid < NK) {
        int p = blk * NK + tid;
        node_s[tid] = order[ph * NN + p];
        val_s[tid]  = val[ph * NN + p];
        rcnt[tid] = 0; rfill[tid] = 0;
    }
    int e0 = bp * CAP_BP;
    int ne = min(fill[bp], CAP_BP);
    for (int t = tid; t < ne; t += 256) el_s[t] = elist[e0 + t];
    __syncthreads();
    for (int t = tid; t < ne; t += 256)
        atomicAdd(&rcnt[el_s[t] & 0xffff], 1);
    __syncthreads();
    // inclusive scan of rcnt over 128 rows: shfl_up + carry
    int v = 0;
    if (tid < NK) {
        v = rcnt[tid];
        int lane = tid & 63;
#pragma unroll
        for (int off = 1; off < 64; off <<= 1) {
            int u = __shfl_up(v, off, 64);
            v += (lane >= off) ? u : 0;
        }
        if (tid == 63) scan_tot = v;
    }
    __syncthreads();
    if (tid < NK) rend[tid] = v + ((tid >= 64) ? scan_tot : 0);
    __syncthreads();
    for (int t = tid; t < ne; t += 256) {
        unsigned ent = el_s[t];
        int ss = ent & 0xffff, sd = ent >> 16;
        int slot = atomicAdd(&rfill[ss], 1);
        int p0 = rend[ss] - rcnt[ss] + slot;
        es_meta[p0] = ((unsigned)ss << 16) | (unsigned)node_s[sd];
        es_coef[p0] = val_s[ss] * val_s[sd] * val_s[sd];
    }
    __syncthreads();
    size_t gb = (size_t)b * NN * DHID + tid;
    float hsum = 0.f, m = 0.f;
    int prev = -1;
#pragma unroll 4
    for (int i = 0; i < ne; ++i) {
        unsigned md = es_meta[i];
        int row = (int)(md >> 16);
        float g = bf2f(Gbf[gb + (size_t)(md & 0xffffu) * DHID]);
        float c = es_coef[i];
        bool flush = (row != prev);
        hsum += flush ? fmaxf(m, 0.f) : 0.f;
        m = flush ? c * g : fmaf(c, g, m);
        prev = row;
    }
    hsum += fmaxf(m, 0.f);
    hvec[tid] = hsum * (1.0f / NK);
    __syncthreads();
    if (tid < NCLS) {
        float s = 0.f;
        for (int q = 0; q < DHID; ++q) s = fmaf(hvec[q], Wo[q * NCLS + tid], s);
        logits_bp[bp * NCLS + tid] = s;
    }
}

// head-mean + log_softmax -> (8,32,16)
__global__ void k10_final(const float* __restrict__ logits_bp, float* __restrict__ out) {
    int t = threadIdx.x;                 // 256 = 8*32
    int b = t >> 5, blk = t & 31;
    float v[NCLS];
#pragma unroll
    for (int c = 0; c < NCLS; ++c) {
        float s = 0.f;
        for (int hh = 0; hh < NH; ++hh)
            s += logits_bp[(((hh * NB + b) * NJ) + blk) * NCLS + c];
        v[c] = s * 0.25f;
    }
    float mx = v[0];
#pragma unroll
    for (int c = 1; c < NCLS; ++c) mx = fmaxf(mx, v[c]);
    float se = 0.f;
#pragma unroll
    for (int c = 0; c < NCLS; ++c) se += expf(v[c] - mx);
    float lse = logf(se);
#pragma unroll
    for (int c = 0; c < NCLS; ++c) out[t * NCLS + c] = v[c] - mx - lse;
}

extern "C" void kernel_launch(void* const* d_in, const int* in_sizes, int n_in,
                              void* d_out, int out_size, void* d_ws, size_t ws_size,
                              hipStream_t stream) {
    const float* x  = (const float*)d_in[0];
    const float* wr = (const float*)d_in[1];
    const float* W1 = (const float*)d_in[2];
    const float* Wo = (const float*)d_in[3];
    const int*   ei = (const int*)d_in[4];

    char* ws = (char*)d_ws;
    int*      deg_i      = (int*)(ws + 0);          // 128 KB
    float*    rdeg       = (float*)(ws + 131072);   // 128 KB
    float*    scores_pre = (float*)(ws + 262144);   // 512 KB
    int*      iscore     = (int*)(ws + 786432);     // 512 KB
    unsigned short* xbf  = (unsigned short*)(ws + 1310720);   // 8 MB
    unsigned* xappbf     = (unsigned*)(ws + 9699328);         // 8 MB (u32-packed bf16 pairs)
    unsigned short* Gbf  = (unsigned short*)(ws + 18087936);  // 16 MB
    int*      order      = (int*)(ws + 51642368);   // 512 KB
    int*      pos        = (int*)(ws + 52166656);
    float*    val        = (float*)(ws + 53215232);
    int*      fill       = (int*)(ws + 53743616);   // 4 KB (per-bpid count)
    int*      csr_src    = (int*)(ws + 53755904);   // 2 MB (lifetime ends at k4)
    unsigned short* w1t  = (unsigned short*)(ws + 55853056); // 128 KB
    unsigned* elist      = (unsigned*)(ws + 53755904); // 2 MB (aliases csr_src; written at k56)
    float*    logits_bp  = (float*)(ws + 62144512); // 64 KB
    int*      nbase      = (int*)(ws + 62210048);   // 128 KB + 4
    int*      fill2      = (int*)(ws + 62341184);   // 128 KB
    unsigned long long* sorted64 = (unsigned long long*)(ws + 62472256); // 1 MB

    k0_init<<<128, 256, 0, stream>>>(deg_i, fill, fill2);
    k1_deg_prep<<<4864, 256, 0, stream>>>(ei, x, W1, wr, deg_i, xbf, w1t, scores_pre);
    k_prep2<<<129, 256, 0, stream>>>(deg_i, rdeg, nbase);
    k3c_fill_csr<<<2048, 256, 0, stream>>>(ei, nbase, fill2, csr_src);
    k4_gather<<<8704, 256, 0, stream>>>(csr_src, nbase, rdeg, x, xbf, scores_pre, xappbf, iscore);
    kg5a<<<768, 256, 0, stream>>>(xbf, (const unsigned short*)xappbf, w1t, Gbf,
                                  scores_pre, iscore, deg_i, sorted64);
    k5b_rank<<<512, 256, 0, stream>>>(sorted64, order, pos, val);
    k56_bin<<<256, 256, 0, stream>>>(ei, pos, fill, elist);
    k9_block<<<BPB, 256, 0, stream>>>(Gbf, order, val, fill, elist, Wo, logits_bp);
    k10_final<<<1, 256, 0, stream>>>(logits_bp, (float*)d_out);
}